// Round 8
// baseline (197.437 us; speedup 1.0000x reference)
//
#include <hip/hip_runtime.h>
#include <hip/hip_bf16.h>
#include <stdint.h>
#include <stddef.h>

#define NROWS 8192
#define DDIM  512              // floats per input row; ALSO bytes per fp8 row
#define TILE  128
#define KHALF 256              // fp8 K-bytes per LDS stage (full K = 2 stages, resident)
#define NBLK  (NROWS / TILE)   // 64
#define LDS_BYTES (4 * TILE * KHALF)   // As0|Bs0|As1|Bs1 = 128 KB

static_assert(NBLK == 64, "bj extraction assumes 64 col-blocks");

typedef float f32x4 __attribute__((ext_vector_type(4)));
typedef long  v2l  __attribute__((ext_vector_type(2)));   // one 16-B LDS read

// async global->LDS, 16B per lane; LDS dest is wave-uniform base + lane*16
__device__ __forceinline__ void async_copy16(const void* g, void* l) {
    __builtin_amdgcn_global_load_lds(
        (const __attribute__((address_space(1))) uint32_t*)g,
        (__attribute__((address_space(3))) uint32_t*)l,
        16, 0, 0);
}

// -------- prep: zero accumulators + normalize both matrices to fp8 e4m3 --------
// grid = 4096: blocks [0,2048) cxr->cn8, [2048,4096) ehr->en8.
// blocks [0,64) zero rowsum/colsum (64*256 = 16384 = 2N floats); block 0 zeroes out[0].
__global__ __launch_bounds__(256) void prep_kernel(
    const float* __restrict__ CXR, const float* __restrict__ EHR,
    uint32_t* __restrict__ CN8, uint32_t* __restrict__ EN8,
    float* __restrict__ rowsum /* colsum follows contiguously */,
    float* __restrict__ out)
{
    if (blockIdx.x < 64) {
        rowsum[blockIdx.x * 256 + threadIdx.x] = 0.f;
        if (blockIdx.x == 0 && threadIdx.x == 0) out[0] = 0.f;
    }
    const int half = (blockIdx.x >= 2048);
    const float* X = half ? EHR : CXR;
    uint32_t* Y = half ? EN8 : CN8;
    const int row  = (blockIdx.x & 2047) * 4 + (threadIdx.x >> 6);
    const int lane = threadIdx.x & 63;
    const float* xr = X + (size_t)row * DDIM;
    float4 v0 = ((const float4*)xr)[lane];        // elems lane*4   .. +3
    float4 v1 = ((const float4*)xr)[lane + 64];   // elems 256+lane*4 .. +3
    float ss = v0.x*v0.x + v0.y*v0.y + v0.z*v0.z + v0.w*v0.w
             + v1.x*v1.x + v1.y*v1.y + v1.z*v1.z + v1.w*v1.w;
    #pragma unroll
    for (int d = 1; d < 64; d <<= 1) ss += __shfl_xor(ss, d);
    const float sc = 1.0f / fmaxf(sqrtf(ss), 1e-8f);
    uint32_t* yr = Y + (size_t)row * (DDIM / 4);
    int w0 = __builtin_amdgcn_cvt_pk_fp8_f32(v0.x*sc, v0.y*sc, 0, false);
    w0     = __builtin_amdgcn_cvt_pk_fp8_f32(v0.z*sc, v0.w*sc, w0, true);
    int w1 = __builtin_amdgcn_cvt_pk_fp8_f32(v1.x*sc, v1.y*sc, 0, false);
    w1     = __builtin_amdgcn_cvt_pk_fp8_f32(v1.z*sc, v1.w*sc, w1, true);
    yr[lane]      = (uint32_t)w0;   // bytes = elems lane*4..+3 in k order
    yr[lane + 64] = (uint32_t)w1;
}

// -------- fused S = cn·enT fp8 GEMM (full-K-resident restructure) + loss epilogue -----
// 512 threads = 8 waves, wave tile 64x32 (wi=(wv&1)*64, wj=(wv>>1)*32).
// K=512 fits entirely in 128 KB dynamic LDS (two 64 KB halves). K-loop has TWO
// barriers total (vs 8 in the 4-stage round-7 kernel): stage half-0, barrier,
// issue half-1 prefetch, compute half-0 (covers prefetch), barrier, compute
// half-1. Removes the per-stage vmcnt(0)+s_barrier drain that capped round 7.
// LDS layout: row r (0..127) = sixteen 16-B units; unit u at slot u^(r&7)
// (conflict-free fragment reads, proven rounds 1/7). Staging lane l of copy c
// (rows R0=w*16+4c..+3) fetches global unit (l&15)^((R0&4)|(l>>4)).
__global__ __launch_bounds__(512, 2) void gemm_loss_kernel(
    const uint8_t* __restrict__ A,   // cn fp8 [N][512 B]
    const uint8_t* __restrict__ B,   // en fp8 [N][512 B]
    const float* __restrict__ temp_p,
    float* __restrict__ rowsum,
    float* __restrict__ colsum,
    float* __restrict__ diagv)
{
    extern __shared__ uint8_t smem[];
    uint8_t* As[2] = { smem,             smem + 2 * TILE * KHALF };
    uint8_t* Bs[2] = { smem + TILE * KHALF, smem + 3 * TILE * KHALF };

    const int tid  = threadIdx.x;
    const int lane = tid & 63;
    const int wv   = tid >> 6;          // wave 0..7
    const int wi   = (wv & 1) * 64;     // wave row offset in tile
    const int wj   = (wv >> 1) * 32;    // wave col offset in tile
    const int lcol = lane & 15;
    const int q    = lane >> 4;

    const int bi = blockIdx.x & (NBLK - 1);
    const int bj = blockIdx.x >> 6;
    const int row0 = bi * TILE;
    const int col0 = bj * TILE;

    // staging geometry: wave wv stages rows [wv*16, wv*16+16) of A and B,
    // 4 copy-instructions each (4 rows x 1 KB per instruction).
    const int ro = lane >> 4;            // row within 4-row chunk (0..3)
    const uint8_t* Agb = A + (size_t)(row0 + wv * 16 + ro) * DDIM;
    const uint8_t* Bgb = B + (size_t)(col0 + wv * 16 + ro) * DDIM;

    #pragma unroll
    for (int s = 0; s < 2; ++s) {        // stage s covers k-bytes [s*256, s*256+256)
        if (s == 1) __syncthreads();     // drain stage-0 before compute uses it...
                                          // (placed so stage-1 issue happens AFTER)
        #pragma unroll
        for (int c = 0; c < 4; ++c) {
            const int R0 = wv * 16 + c * 4;
            const int gu = (lane & 15) ^ ((R0 & 4) | ro);   // swizzle inverse
            const size_t goff = (size_t)(c * 4) * DDIM + s * KHALF + gu * 16;
            async_copy16(Agb + goff, As[s] + R0 * KHALF + lane * 16);
            async_copy16(Bgb + goff, Bs[s] + R0 * KHALF + lane * 16);
        }
    }
    // NOTE: first __syncthreads above (before s==1 issue) drains only stage-0
    // loads... vmcnt(0) also waits for nothing else since stage-1 not yet issued.

    f32x4 acc[4][2] = {};
    const float invT = 1.0f / temp_p[0];
    const float M = invT;

    #pragma unroll
    for (int s = 0; s < 2; ++s) {
        if (s == 1) __syncthreads();     // drain stage-1 prefetch (covered by stage-0 compute)
        #pragma unroll
        for (int kk2 = 0; kk2 < 4; ++kk2) {   // 16-B unit u per lane; 2 K=32 windows each
            const int u = kk2 * 4 + q;
            long aflo[4], afhi[4];
            #pragma unroll
            for (int mt = 0; mt < 4; ++mt) {
                const int r = wi + mt * 16 + lcol;
                v2l a16 = *(const v2l*)&As[s][r * KHALF + (u ^ (r & 7)) * 16];
                aflo[mt] = a16.x; afhi[mt] = a16.y;
            }
            #pragma unroll
            for (int nt = 0; nt < 2; ++nt) {
                const int r = wj + nt * 16 + lcol;
                v2l b16 = *(const v2l*)&Bs[s][r * KHALF + (u ^ (r & 7)) * 16];
                #pragma unroll
                for (int mt = 0; mt < 4; ++mt)
                    acc[mt][nt] = __builtin_amdgcn_mfma_f32_16x16x32_fp8_fp8(
                        aflo[mt], b16.x, acc[mt][nt], 0, 0, 0);
                #pragma unroll
                for (int mt = 0; mt < 4; ++mt)
                    acc[mt][nt] = __builtin_amdgcn_mfma_f32_16x16x32_fp8_fp8(
                        afhi[mt], b16.y, acc[mt][nt], 0, 0, 0);
            }
        }
    }

    // ---- epilogue: e = exp(s - M), M = 1/T (max possible), diag excluded ----
    float rs[4][4];   // per-lane row partials [mt][reg]
    float cs[2];      // per-lane col partials [nt]
    #pragma unroll
    for (int mt = 0; mt < 4; ++mt)
        #pragma unroll
        for (int r = 0; r < 4; ++r) rs[mt][r] = 0.f;
    cs[0] = cs[1] = 0.f;

    #pragma unroll
    for (int mt = 0; mt < 4; ++mt) {
        #pragma unroll
        for (int nt = 0; nt < 2; ++nt) {
            #pragma unroll
            for (int r = 0; r < 4; ++r) {
                // C/D layout: col = lane&15, row = quad*4 + reg  [m89/m91]
                const int gi = row0 + wi + mt * 16 + q * 4 + r;
                const int gj = col0 + wj + nt * 16 + lcol;
                const float sv = acc[mt][nt][r] * invT;
                float e;
                if (gi == gj) { diagv[gi] = sv; e = 0.f; }
                else          { e = __expf(sv - M); }
                rs[mt][r] += e;
                cs[nt]    += e;
            }
        }
    }

    // row sums: reduce across the 16 columns (lane bits 0..3)
    #pragma unroll
    for (int d = 1; d < 16; d <<= 1)
        #pragma unroll
        for (int mt = 0; mt < 4; ++mt)
            #pragma unroll
            for (int r = 0; r < 4; ++r)
                rs[mt][r] += __shfl_xor(rs[mt][r], d);

    // col sums: reduce across the 4 quads (lane bits 4..5)
    #pragma unroll
    for (int d = 16; d < 64; d <<= 1)
        #pragma unroll
        for (int nt = 0; nt < 2; ++nt)
            cs[nt] += __shfl_xor(cs[nt], d);

    if (lcol == 0) {
        #pragma unroll
        for (int mt = 0; mt < 4; ++mt)
            #pragma unroll
            for (int r = 0; r < 4; ++r)
                atomicAdd(&rowsum[row0 + wi + mt * 16 + q * 4 + r], rs[mt][r]);
    }
    if (q == 0) {
        #pragma unroll
        for (int nt = 0; nt < 2; ++nt)
            atomicAdd(&colsum[col0 + wj + nt * 16 + lcol], cs[nt]);
    }
}

// -------- final scalar: loss = mean_i( 2M + log(rowsum_i) + log(colsum_i) - 2*diag_i ) ----
__global__ __launch_bounds__(256) void finalize_kernel(
    const float* __restrict__ rowsum, const float* __restrict__ colsum,
    const float* __restrict__ diagv,  const float* __restrict__ temp_p,
    float* __restrict__ out)
{
    __shared__ float red[4];
    const float M = 1.0f / temp_p[0];
    const int i = blockIdx.x * 256 + threadIdx.x;
    float s = 2.f * M + logf(rowsum[i]) + logf(colsum[i]) - 2.f * diagv[i];
    #pragma unroll
    for (int d = 1; d < 64; d <<= 1) s += __shfl_xor(s, d);
    if ((threadIdx.x & 63) == 0) red[threadIdx.x >> 6] = s;
    __syncthreads();
    if (threadIdx.x == 0)
        atomicAdd(out, (red[0] + red[1] + red[2] + red[3]) / (float)NROWS);
}

extern "C" void kernel_launch(void* const* d_in, const int* in_sizes, int n_in,
                              void* d_out, int out_size, void* d_ws, size_t ws_size,
                              hipStream_t stream) {
    (void)in_sizes; (void)n_in; (void)out_size; (void)ws_size;
    const float* cxr    = (const float*)d_in[0];
    const float* ehr    = (const float*)d_in[1];
    const float* temp_p = (const float*)d_in[2];
    float* out = (float*)d_out;

    // workspace: rowsum[N] | colsum[N] | diag[N] | cn fp8 [N*512B] | en fp8 (~8.1 MB)
    float* rowsum = (float*)d_ws;
    float* colsum = rowsum + NROWS;
    float* diagv  = colsum + NROWS;
    uint32_t* cn8 = (uint32_t*)(diagv + NROWS);            // 16B-aligned (96 KB offset)
    uint32_t* en8 = cn8 + (size_t)NROWS * (DDIM / 4);
    const uint8_t* cnb = (const uint8_t*)cn8;
    const uint8_t* enb = (const uint8_t*)en8;

    // allow 128 KB dynamic LDS (default cap is 64 KB); idempotent, capture-safe
    hipFuncSetAttribute(reinterpret_cast<const void*>(gemm_loss_kernel),
                        hipFuncAttributeMaxDynamicSharedMemorySize, LDS_BYTES);

    prep_kernel<<<4096, 256, 0, stream>>>(cxr, ehr, cn8, en8, rowsum, out);
    gemm_loss_kernel<<<NBLK * NBLK, 512, LDS_BYTES, stream>>>(cnb, enb, temp_p, rowsum, colsum, diagv);
    finalize_kernel<<<NROWS / 256, 256, 0, stream>>>(rowsum, colsum, diagv, temp_p, out);
}

// Round 9
// 162.160 us; speedup vs baseline: 1.2175x; 1.2175x over previous
//
#include <hip/hip_runtime.h>
#include <hip/hip_bf16.h>
#include <stdint.h>
#include <stddef.h>

#define NROWS 8192
#define DDIM  512              // floats per input row; ALSO bytes per fp8 row
#define TILE  128
#define BKB   128              // fp8 K-elements (=bytes) per LDS stage
#define NBLK  (NROWS / TILE)   // 64

static_assert(NBLK == 64, "bj extraction assumes 64 col-blocks");

typedef float f32x16 __attribute__((ext_vector_type(16)));
typedef long  v2l   __attribute__((ext_vector_type(2)));   // one 16-B LDS read

// async global->LDS, 16B per lane; LDS dest is wave-uniform base + lane*16
__device__ __forceinline__ void async_copy16(const void* g, void* l) {
    __builtin_amdgcn_global_load_lds(
        (const __attribute__((address_space(1))) uint32_t*)g,
        (__attribute__((address_space(3))) uint32_t*)l,
        16, 0, 0);
}

// -------- prep: zero accumulators + normalize both matrices to fp8 e4m3 --------
// grid = 4096: blocks [0,2048) cxr->cn8, [2048,4096) ehr->en8.
// blocks [0,64) zero rowsum/colsum (64*256 = 16384 = 2N floats); block 0 zeroes out[0].
__global__ __launch_bounds__(256) void prep_kernel(
    const float* __restrict__ CXR, const float* __restrict__ EHR,
    uint32_t* __restrict__ CN8, uint32_t* __restrict__ EN8,
    float* __restrict__ rowsum /* colsum follows contiguously */,
    float* __restrict__ out)
{
    if (blockIdx.x < 64) {
        rowsum[blockIdx.x * 256 + threadIdx.x] = 0.f;
        if (blockIdx.x == 0 && threadIdx.x == 0) out[0] = 0.f;
    }
    const int half = (blockIdx.x >= 2048);
    const float* X = half ? EHR : CXR;
    uint32_t* Y = half ? EN8 : CN8;
    const int row  = (blockIdx.x & 2047) * 4 + (threadIdx.x >> 6);
    const int lane = threadIdx.x & 63;
    const float* xr = X + (size_t)row * DDIM;
    float4 v0 = ((const float4*)xr)[lane];        // elems lane*4   .. +3
    float4 v1 = ((const float4*)xr)[lane + 64];   // elems 256+lane*4 .. +3
    float ss = v0.x*v0.x + v0.y*v0.y + v0.z*v0.z + v0.w*v0.w
             + v1.x*v1.x + v1.y*v1.y + v1.z*v1.z + v1.w*v1.w;
    #pragma unroll
    for (int d = 1; d < 64; d <<= 1) ss += __shfl_xor(ss, d);
    const float sc = 1.0f / fmaxf(sqrtf(ss), 1e-8f);
    uint32_t* yr = Y + (size_t)row * (DDIM / 4);
    int w0 = __builtin_amdgcn_cvt_pk_fp8_f32(v0.x*sc, v0.y*sc, 0, false);
    w0     = __builtin_amdgcn_cvt_pk_fp8_f32(v0.z*sc, v0.w*sc, w0, true);
    int w1 = __builtin_amdgcn_cvt_pk_fp8_f32(v1.x*sc, v1.y*sc, 0, false);
    w1     = __builtin_amdgcn_cvt_pk_fp8_f32(v1.z*sc, v1.w*sc, w1, true);
    yr[lane]      = (uint32_t)w0;   // bytes = elems lane*4..+3 in k order
    yr[lane + 64] = (uint32_t)w1;
}

// -------- fused S = cn·enT fp8 GEMM (32x32x16 shape) + exp + reductions --------
// Round-7 skeleton (4 stages, 2 barriers/stage, 3 blocks/CU co-resident) with the
// MFMA shape switched 16x16x32 -> 32x32x16: half the MFMA instructions at the
// same LDS traffic (2-reg operands feed 2x the FLOP). k-permutation b128 trick
// carried over: lane h=lane>>5 reads contiguous 16-B unit u=2p+h at slot
// u^(r&7); lo 8 B -> MFMA window 2p, hi -> window 2p+1 (consistent permutation
// on A and B => dot products unchanged; conflict-free, proven rounds 1/7).
// Wave tile 64x64 = 2x2 tiles of 32x32; acc 64 AGPRs.
__global__ __launch_bounds__(256, 2) void gemm_loss_kernel(
    const uint8_t* __restrict__ A,   // cn fp8 [N][512 B]
    const uint8_t* __restrict__ B,   // en fp8 [N][512 B]
    const float* __restrict__ temp_p,
    float* __restrict__ rowsum,
    float* __restrict__ colsum,
    float* __restrict__ diagv)
{
    __shared__ uint8_t As[TILE * BKB];   // 16 KB
    __shared__ uint8_t Bs[TILE * BKB];   // 16 KB

    const int tid  = threadIdx.x;
    const int lane = tid & 63;
    const int wv   = tid >> 6;          // wave 0..3
    const int wi   = (wv >> 1) * 64;    // wave row offset in tile
    const int wj   = (wv & 1) * 64;     // wave col offset in tile
    const int lm   = lane & 31;         // m/n index within 32x32 tile
    const int h    = lane >> 5;         // k-half selector (0/1)

    const int bi = blockIdx.x & (NBLK - 1);
    const int bj = blockIdx.x >> 6;
    const int row0 = bi * TILE;
    const int col0 = bj * TILE;

    // staging: wave wv loads rows [wv*32, wv*32+32) of both tiles, 4 chunks of 8 rows
    const int sr = lane >> 3;            // row within 8-row chunk
    const int su = (lane & 7) ^ sr;      // 16B-unit fetched by this lane (swizzle inverse)
    const uint8_t* Ag = A + (size_t)(row0 + wv * 32 + sr) * DDIM + su * 16;
    const uint8_t* Bg = B + (size_t)(col0 + wv * 32 + sr) * DDIM + su * 16;

    // hoisted LDS read offsets: [mt|nt][pair]
    int aoff[2][4], boff[2][4];
    #pragma unroll
    for (int mt = 0; mt < 2; ++mt) {
        const int ra = wi + mt * 32 + lm;
        const int rb = wj + mt * 32 + lm;
        #pragma unroll
        for (int p = 0; p < 4; ++p) {
            const int u = 2 * p + h;
            aoff[mt][p] = ra * BKB + ((u ^ (ra & 7)) * 16);
            boff[mt][p] = rb * BKB + ((u ^ (rb & 7)) * 16);
        }
    }

    f32x16 acc[2][2] = {};

    for (int k0 = 0; k0 < DDIM; k0 += BKB) {   // 4 stages
        __syncthreads();   // previous stage's LDS reads done before overwrite
        #pragma unroll
        for (int c = 0; c < 4; ++c) {
            async_copy16(Ag + (size_t)(c * 8) * DDIM + k0, &As[(wv * 32 + c * 8) * BKB]);
            async_copy16(Bg + (size_t)(c * 8) * DDIM + k0, &Bs[(wv * 32 + c * 8) * BKB]);
        }
        __syncthreads();   // drains vmcnt before s_barrier

        #pragma unroll
        for (int p = 0; p < 4; ++p) {          // each pair covers two K=16 windows
            long alo[2], ahi[2];
            #pragma unroll
            for (int mt = 0; mt < 2; ++mt) {
                v2l a16 = *(const v2l*)&As[aoff[mt][p]];
                alo[mt] = a16.x; ahi[mt] = a16.y;
            }
            #pragma unroll
            for (int nt = 0; nt < 2; ++nt) {
                v2l b16 = *(const v2l*)&Bs[boff[nt][p]];
                #pragma unroll
                for (int mt = 0; mt < 2; ++mt)
                    acc[mt][nt] = __builtin_amdgcn_mfma_f32_32x32x16_fp8_fp8(
                        alo[mt], b16.x, acc[mt][nt], 0, 0, 0);
                #pragma unroll
                for (int mt = 0; mt < 2; ++mt)
                    acc[mt][nt] = __builtin_amdgcn_mfma_f32_32x32x16_fp8_fp8(
                        ahi[mt], b16.y, acc[mt][nt], 0, 0, 0);
            }
        }
    }

    // ---- epilogue: e = exp(s - M), M = 1/T (max possible), diag excluded ----
    const float invT = 1.0f / temp_p[0];
    const float M = invT;

    float rs[2][16];  // per-lane row partials [mt][reg]
    float cs[2];      // per-lane col partials [nt]
    #pragma unroll
    for (int mt = 0; mt < 2; ++mt)
        #pragma unroll
        for (int r = 0; r < 16; ++r) rs[mt][r] = 0.f;
    cs[0] = cs[1] = 0.f;

    #pragma unroll
    for (int mt = 0; mt < 2; ++mt) {
        #pragma unroll
        for (int nt = 0; nt < 2; ++nt) {
            #pragma unroll
            for (int r = 0; r < 16; ++r) {
                // 32x32 C/D layout: col = lane&31, row = (reg&3)+8*(reg>>2)+4*h  [m74/m101]
                const int gi = row0 + wi + mt * 32 + (r & 3) + 8 * (r >> 2) + 4 * h;
                const int gj = col0 + wj + nt * 32 + lm;
                const float sv = acc[mt][nt][r] * invT;
                float e;
                if (gi == gj) { diagv[gi] = sv; e = 0.f; }
                else          { e = __expf(sv - M); }
                rs[mt][r] += e;
                cs[nt]    += e;
            }
        }
    }

    // row sums: reduce across the 32 columns (lane bits 0..4)
    #pragma unroll
    for (int d = 1; d < 32; d <<= 1)
        #pragma unroll
        for (int mt = 0; mt < 2; ++mt)
            #pragma unroll
            for (int r = 0; r < 16; ++r)
                rs[mt][r] += __shfl_xor(rs[mt][r], d);

    // col sums: sum the two k-half lane groups (lane bit 5)
    cs[0] += __shfl_xor(cs[0], 32);
    cs[1] += __shfl_xor(cs[1], 32);

    if (lm == 0) {   // lanes 0 (h=0) and 32 (h=1) write their h's rows
        #pragma unroll
        for (int mt = 0; mt < 2; ++mt)
            #pragma unroll
            for (int r = 0; r < 16; ++r)
                atomicAdd(&rowsum[row0 + wi + mt * 32 + (r & 3) + 8 * (r >> 2) + 4 * h],
                          rs[mt][r]);
    }
    if (h == 0) {
        #pragma unroll
        for (int nt = 0; nt < 2; ++nt)
            atomicAdd(&colsum[col0 + wj + nt * 32 + lm], cs[nt]);
    }
}

// -------- final scalar: loss = mean_i( 2M + log(rowsum_i) + log(colsum_i) - 2*diag_i ) ----
__global__ __launch_bounds__(256) void finalize_kernel(
    const float* __restrict__ rowsum, const float* __restrict__ colsum,
    const float* __restrict__ diagv,  const float* __restrict__ temp_p,
    float* __restrict__ out)
{
    __shared__ float red[4];
    const float M = 1.0f / temp_p[0];
    const int i = blockIdx.x * 256 + threadIdx.x;
    float s = 2.f * M + logf(rowsum[i]) + logf(colsum[i]) - 2.f * diagv[i];
    #pragma unroll
    for (int d = 1; d < 64; d <<= 1) s += __shfl_xor(s, d);
    if ((threadIdx.x & 63) == 0) red[threadIdx.x >> 6] = s;
    __syncthreads();
    if (threadIdx.x == 0)
        atomicAdd(out, (red[0] + red[1] + red[2] + red[3]) / (float)NROWS);
}

extern "C" void kernel_launch(void* const* d_in, const int* in_sizes, int n_in,
                              void* d_out, int out_size, void* d_ws, size_t ws_size,
                              hipStream_t stream) {
    (void)in_sizes; (void)n_in; (void)out_size; (void)ws_size;
    const float* cxr    = (const float*)d_in[0];
    const float* ehr    = (const float*)d_in[1];
    const float* temp_p = (const float*)d_in[2];
    float* out = (float*)d_out;

    // workspace: rowsum[N] | colsum[N] | diag[N] | cn fp8 [N*512B] | en fp8 (~8.1 MB)
    float* rowsum = (float*)d_ws;
    float* colsum = rowsum + NROWS;
    float* diagv  = colsum + NROWS;
    uint32_t* cn8 = (uint32_t*)(diagv + NROWS);            // 16B-aligned (96 KB offset)
    uint32_t* en8 = cn8 + (size_t)NROWS * (DDIM / 4);
    const uint8_t* cnb = (const uint8_t*)cn8;
    const uint8_t* enb = (const uint8_t*)en8;

    prep_kernel<<<4096, 256, 0, stream>>>(cxr, ehr, cn8, en8, rowsum, out);
    gemm_loss_kernel<<<NBLK * NBLK, 256, 0, stream>>>(cnb, enb, temp_p, rowsum, colsum, diagv);
    finalize_kernel<<<NROWS / 256, 256, 0, stream>>>(rowsum, colsum, diagv, temp_p, out);
}

// Round 10
// 136.427 us; speedup vs baseline: 1.4472x; 1.1886x over previous
//
#include <hip/hip_runtime.h>
#include <hip/hip_bf16.h>
#include <stdint.h>
#include <stddef.h>

#define NROWS 8192
#define DDIM  512              // floats per input row; ALSO bytes per fp8 row
#define TILE  128
#define BKB   128              // fp8 K-elements (=bytes) per LDS stage
#define NBLK  (NROWS / TILE)   // 64

static_assert(NBLK == 64, "bj extraction assumes 64 col-blocks");

typedef float f32x4 __attribute__((ext_vector_type(4)));
typedef long  v2l  __attribute__((ext_vector_type(2)));   // one 16-B LDS read

// async global->LDS, 16B per lane; LDS dest is wave-uniform base + lane*16
__device__ __forceinline__ void async_copy16(const void* g, void* l) {
    __builtin_amdgcn_global_load_lds(
        (const __attribute__((address_space(1))) uint32_t*)g,
        (__attribute__((address_space(3))) uint32_t*)l,
        16, 0, 0);
}

// -------- prep: zero accumulators + normalize both matrices to fp8 e4m3 --------
// grid = 4096: blocks [0,2048) cxr->cn8, [2048,4096) ehr->en8.
// blocks [0,64) zero rowsum/colsum (64*256 = 16384 = 2N floats); block 0 zeroes out[0].
__global__ __launch_bounds__(256) void prep_kernel(
    const float* __restrict__ CXR, const float* __restrict__ EHR,
    uint32_t* __restrict__ CN8, uint32_t* __restrict__ EN8,
    float* __restrict__ rowsum /* colsum follows contiguously */,
    float* __restrict__ out)
{
    if (blockIdx.x < 64) {
        rowsum[blockIdx.x * 256 + threadIdx.x] = 0.f;
        if (blockIdx.x == 0 && threadIdx.x == 0) out[0] = 0.f;
    }
    const int half = (blockIdx.x >= 2048);
    const float* X = half ? EHR : CXR;
    uint32_t* Y = half ? EN8 : CN8;
    const int row  = (blockIdx.x & 2047) * 4 + (threadIdx.x >> 6);
    const int lane = threadIdx.x & 63;
    const float* xr = X + (size_t)row * DDIM;
    float4 v0 = ((const float4*)xr)[lane];        // elems lane*4   .. +3
    float4 v1 = ((const float4*)xr)[lane + 64];   // elems 256+lane*4 .. +3
    float ss = v0.x*v0.x + v0.y*v0.y + v0.z*v0.z + v0.w*v0.w
             + v1.x*v1.x + v1.y*v1.y + v1.z*v1.z + v1.w*v1.w;
    #pragma unroll
    for (int d = 1; d < 64; d <<= 1) ss += __shfl_xor(ss, d);
    const float sc = 1.0f / fmaxf(sqrtf(ss), 1e-8f);
    uint32_t* yr = Y + (size_t)row * (DDIM / 4);
    int w0 = __builtin_amdgcn_cvt_pk_fp8_f32(v0.x*sc, v0.y*sc, 0, false);
    w0     = __builtin_amdgcn_cvt_pk_fp8_f32(v0.z*sc, v0.w*sc, w0, true);
    int w1 = __builtin_amdgcn_cvt_pk_fp8_f32(v1.x*sc, v1.y*sc, 0, false);
    w1     = __builtin_amdgcn_cvt_pk_fp8_f32(v1.z*sc, v1.w*sc, w1, true);
    yr[lane]      = (uint32_t)w0;   // bytes = elems lane*4..+3 in k order
    yr[lane + 64] = (uint32_t)w1;
}

// -------- fused S = cn·enT fp8 GEMM (non-scaled 16x16x32) + exp + reductions --------
// Round-7 kernel with ONE change: __launch_bounds__(256,4). VGPR 60 + AGPR 64
// = 124 unified fits the 128-reg cap, so 4 blocks/CU co-reside (was ~2.8),
// doubling the independent barrier-phases that hide the vmcnt(0) drain.
// 256 threads / 4 waves, wave tile 64x64, acc 4x4 f32x4 (AGPRs).
// Fragment reads: conflict-free b128 via k-permutation — lane (m,q) reads
// 16 B at unit u=kk2*4+q, slot u^(r&7); lo 8 B feed MFMA window 2kk2, hi feed
// 2kk2+1 (same permutation on A and B => dot products unchanged).
__global__ __launch_bounds__(256, 4) void gemm_loss_kernel(
    const uint8_t* __restrict__ A,   // cn fp8 [N][512 B]
    const uint8_t* __restrict__ B,   // en fp8 [N][512 B]
    const float* __restrict__ temp_p,
    float* __restrict__ rowsum,
    float* __restrict__ colsum,
    float* __restrict__ diagv)
{
    __shared__ uint8_t As[TILE * BKB];   // 16 KB
    __shared__ uint8_t Bs[TILE * BKB];   // 16 KB

    const int tid  = threadIdx.x;
    const int lane = tid & 63;
    const int wv   = tid >> 6;          // wave 0..3
    const int wi   = (wv >> 1) * 64;    // wave row offset in tile
    const int wj   = (wv & 1) * 64;     // wave col offset in tile
    const int lcol = lane & 15;
    const int q    = lane >> 4;

    const int bi = blockIdx.x & (NBLK - 1);
    const int bj = blockIdx.x >> 6;
    const int row0 = bi * TILE;
    const int col0 = bj * TILE;

    // staging: wave wv loads rows [wv*32, wv*32+32) of both tiles, 4 chunks of 8 rows
    const int sr = lane >> 3;            // row within 8-row chunk
    const int su = (lane & 7) ^ sr;      // 16B-unit fetched by this lane (swizzle inverse)
    const uint8_t* Ag = A + (size_t)(row0 + wv * 32 + sr) * DDIM + su * 16;
    const uint8_t* Bg = B + (size_t)(col0 + wv * 32 + sr) * DDIM + su * 16;

    f32x4 acc[4][4] = {};

    for (int k0 = 0; k0 < DDIM; k0 += BKB) {   // 4 stages
        __syncthreads();   // previous stage's LDS reads done before overwrite
        #pragma unroll
        for (int c = 0; c < 4; ++c) {
            async_copy16(Ag + (size_t)(c * 8) * DDIM + k0, &As[(wv * 32 + c * 8) * BKB]);
            async_copy16(Bg + (size_t)(c * 8) * DDIM + k0, &Bs[(wv * 32 + c * 8) * BKB]);
        }
        __syncthreads();   // drains vmcnt before s_barrier

        #pragma unroll
        for (int kk2 = 0; kk2 < 2; ++kk2) {    // each kk2 covers two K=32 windows
            const int u = kk2 * 4 + q;         // this lane's 16B k-unit
            long aflo[4], afhi[4];
            #pragma unroll
            for (int mt = 0; mt < 4; ++mt) {
                const int r = wi + mt * 16 + lcol;
                v2l a16 = *(const v2l*)&As[r * BKB + (u ^ (r & 7)) * 16];
                aflo[mt] = a16.x; afhi[mt] = a16.y;
            }
            // B fragments streamed: one b128 feeds 8 MFMAs (2 windows x 4 m-tiles)
            #pragma unroll
            for (int nt = 0; nt < 4; ++nt) {
                const int r = wj + nt * 16 + lcol;
                v2l b16 = *(const v2l*)&Bs[r * BKB + (u ^ (r & 7)) * 16];
                #pragma unroll
                for (int mt = 0; mt < 4; ++mt)
                    acc[mt][nt] = __builtin_amdgcn_mfma_f32_16x16x32_fp8_fp8(
                        aflo[mt], b16.x, acc[mt][nt], 0, 0, 0);
                #pragma unroll
                for (int mt = 0; mt < 4; ++mt)
                    acc[mt][nt] = __builtin_amdgcn_mfma_f32_16x16x32_fp8_fp8(
                        afhi[mt], b16.y, acc[mt][nt], 0, 0, 0);
            }
        }
    }

    // ---- epilogue: e = exp(s - M), M = 1/T (max possible), diag excluded ----
    const float invT = 1.0f / temp_p[0];
    const float M = invT;

    float rs[4][4];   // per-lane row partials [mt][reg]
    float cs[4];      // per-lane col partials [nt]
    #pragma unroll
    for (int mt = 0; mt < 4; ++mt)
        #pragma unroll
        for (int r = 0; r < 4; ++r) rs[mt][r] = 0.f;
    #pragma unroll
    for (int nt = 0; nt < 4; ++nt) cs[nt] = 0.f;

    #pragma unroll
    for (int mt = 0; mt < 4; ++mt) {
        #pragma unroll
        for (int nt = 0; nt < 4; ++nt) {
            #pragma unroll
            for (int r = 0; r < 4; ++r) {
                // C/D layout: col = lane&15, row = quad*4 + reg  [m89/m91]
                const int gi = row0 + wi + mt * 16 + q * 4 + r;
                const int gj = col0 + wj + nt * 16 + lcol;
                const float sv = acc[mt][nt][r] * invT;
                float e;
                if (gi == gj) { diagv[gi] = sv; e = 0.f; }
                else          { e = __expf(sv - M); }
                rs[mt][r] += e;
                cs[nt]    += e;
            }
        }
    }

    // row sums: reduce across the 16 columns (lane bits 0..3)
    #pragma unroll
    for (int d = 1; d < 16; d <<= 1)
        #pragma unroll
        for (int mt = 0; mt < 4; ++mt)
            #pragma unroll
            for (int r = 0; r < 4; ++r)
                rs[mt][r] += __shfl_xor(rs[mt][r], d);

    // col sums: reduce across the 4 quads (lane bits 4..5)
    #pragma unroll
    for (int d = 16; d < 64; d <<= 1)
        #pragma unroll
        for (int nt = 0; nt < 4; ++nt)
            cs[nt] += __shfl_xor(cs[nt], d);

    if (lcol == 0) {
        #pragma unroll
        for (int mt = 0; mt < 4; ++mt)
            #pragma unroll
            for (int r = 0; r < 4; ++r)
                atomicAdd(&rowsum[row0 + wi + mt * 16 + q * 4 + r], rs[mt][r]);
    }
    if (q == 0) {
        #pragma unroll
        for (int nt = 0; nt < 4; ++nt)
            atomicAdd(&colsum[col0 + wj + nt * 16 + lcol], cs[nt]);
    }
}

// -------- final scalar: loss = mean_i( 2M + log(rowsum_i) + log(colsum_i) - 2*diag_i ) ----
__global__ __launch_bounds__(256) void finalize_kernel(
    const float* __restrict__ rowsum, const float* __restrict__ colsum,
    const float* __restrict__ diagv,  const float* __restrict__ temp_p,
    float* __restrict__ out)
{
    __shared__ float red[4];
    const float M = 1.0f / temp_p[0];
    const int i = blockIdx.x * 256 + threadIdx.x;
    float s = 2.f * M + logf(rowsum[i]) + logf(colsum[i]) - 2.f * diagv[i];
    #pragma unroll
    for (int d = 1; d < 64; d <<= 1) s += __shfl_xor(s, d);
    if ((threadIdx.x & 63) == 0) red[threadIdx.x >> 6] = s;
    __syncthreads();
    if (threadIdx.x == 0)
        atomicAdd(out, (red[0] + red[1] + red[2] + red[3]) / (float)NROWS);
}

extern "C" void kernel_launch(void* const* d_in, const int* in_sizes, int n_in,
                              void* d_out, int out_size, void* d_ws, size_t ws_size,
                              hipStream_t stream) {
    (void)in_sizes; (void)n_in; (void)out_size; (void)ws_size;
    const float* cxr    = (const float*)d_in[0];
    const float* ehr    = (const float*)d_in[1];
    const float* temp_p = (const float*)d_in[2];
    float* out = (float*)d_out;

    // workspace: rowsum[N] | colsum[N] | diag[N] | cn fp8 [N*512B] | en fp8 (~8.1 MB)
    float* rowsum = (float*)d_ws;
    float* colsum = rowsum + NROWS;
    float* diagv  = colsum + NROWS;
    uint32_t* cn8 = (uint32_t*)(diagv + NROWS);            // 16B-aligned (96 KB offset)
    uint32_t* en8 = cn8 + (size_t)NROWS * (DDIM / 4);
    const uint8_t* cnb = (const uint8_t*)cn8;
    const uint8_t* enb = (const uint8_t*)en8;

    prep_kernel<<<4096, 256, 0, stream>>>(cxr, ehr, cn8, en8, rowsum, out);
    gemm_loss_kernel<<<NBLK * NBLK, 256, 0, stream>>>(cnb, enb, temp_p, rowsum, colsum, diagv);
    finalize_kernel<<<NROWS / 256, 256, 0, stream>>>(rowsum, colsum, diagv, temp_p, out);
}